// Round 4
// baseline (782.541 us; speedup 1.0000x reference)
//
#include <hip/hip_runtime.h>
#include <hip/hip_fp16.h>
#include <hip/hip_bf16.h>

// SlotAttention restructured:
//  dots = qs . x   with qs = LN(slots) @ (scale * Wq^T Wk)   (K never materialized)
//  updates = (N/wsum) * (sum_j w_j x_j) @ Wv^T               (V never materialized)
// x = LN(inputs) stored once as fp16. All accumulation fp32. Output fp32.
// R3: tails still ~460us (0.25-1.5 waves/SIMD -> L2 latency exposed).
// R4: re-partition tail GEMMs for TLP: upd 64->512 blocks, gates 384->768,
//     mlp1 256->512, mlp2 128->512 (1 row/block, 2 K-half accumulators).

#define BB 64
#define NN 4096
#define DD 256
#define NSL 8
#define NITER 3

__device__ __forceinline__ float wredsum(float v){
#pragma unroll
  for(int m=32;m;m>>=1) v += __shfl_xor(v, m, 64);
  return v;
}
__device__ __forceinline__ float2 u2f2(unsigned u){ __half2 h; __builtin_memcpy(&h,&u,4); return __half22float2(h); }
__device__ __forceinline__ float sigm(float v){ return 1.0f/(1.0f+__expf(-v)); }

// ---------------- prep: weight transposes + slots broadcast init ----------------
__global__ __launch_bounds__(256) void k_prep(
    const float* __restrict__ Wih, const float* __restrict__ Whh,
    const float* __restrict__ W1,  const float* __restrict__ W2,
    const float* __restrict__ Wv,  const float* __restrict__ sinit,
    float* __restrict__ WihT, float* __restrict__ WhhT,
    float* __restrict__ W1T,  float* __restrict__ W2T,
    float* __restrict__ WvT,  float* __restrict__ slots){
  for(int idx = blockIdx.x*256 + threadIdx.x; idx < 1114112; idx += gridDim.x*256){
    if(idx < 196608){ int d=idx>>8, c=idx&255; WihT[c*768+d] = Wih[idx]; }
    else if(idx < 393216){ int k=idx-196608; int d=k>>8,  c=k&255;  WhhT[c*768+d]  = Whh[k]; }
    else if(idx < 655360){ int k=idx-393216; int d=k>>8,  c=k&255;  W1T[c*1024+d]  = W1[k]; }   // W1 [1024][256]
    else if(idx < 917504){ int k=idx-655360; int d=k>>10, c=k&1023; W2T[c*256+d]   = W2[k]; }   // W2 [256][1024]
    else if(idx < 983040){ int k=idx-917504; int d=k>>8,  c=k&255;  WvT[c*256+d]   = Wv[k]; }
    else { int k=idx-983040; slots[k] = sinit[k&2047]; }                                        // broadcast over b
  }
}

// ---------------- M = scale * Wq^T @ Wk  (M[e][c]) ----------------
__global__ __launch_bounds__(256) void k_M(const float* __restrict__ Wq, const float* __restrict__ Wk,
                                           float* __restrict__ M){
  int e = blockIdx.x, c = threadIdx.x;
  float acc = 0.f;
#pragma unroll 8
  for(int d=0; d<256; d++) acc += Wq[d*256+e]*Wk[d*256+c];
  M[e*256+c] = acc * 0.0625f;  // 256^-0.5
}

// ---------------- x = LN(inputs) -> fp16 ----------------
__global__ __launch_bounds__(256) void k_ln_x(const float* __restrict__ in, const float* __restrict__ g,
                                              const float* __restrict__ bbv, __half* __restrict__ x){
  int row  = blockIdx.x*4 + (threadIdx.x>>6);
  int lane = threadIdx.x&63;
  const float4 v = ((const float4*)(in + (size_t)row*DD))[lane];
  float s  = v.x+v.y+v.z+v.w;
  float ss = v.x*v.x+v.y*v.y+v.z*v.z+v.w*v.w;
  s = wredsum(s); ss = wredsum(ss);
  float m = s*(1.0f/256.0f);
  float r = rsqrtf(ss*(1.0f/256.0f) - m*m + 1e-5f);
  float4 gv = ((const float4*)g)[lane];
  float4 bv = ((const float4*)bbv)[lane];
  float y0=(v.x-m)*r*gv.x+bv.x, y1=(v.y-m)*r*gv.y+bv.y;
  float y2=(v.z-m)*r*gv.z+bv.z, y3=(v.w-m)*r*gv.w+bv.w;
  __half2 h0=__floats2half2_rn(y0,y1), h1=__floats2half2_rn(y2,y3);
  uint2 u; __builtin_memcpy(&u.x,&h0,4); __builtin_memcpy(&u.y,&h1,4);
  ((uint2*)(x + (size_t)row*DD))[lane] = u;
}

// ---------------- per-iter: qs = LN(slots) @ M ----------------
__global__ __launch_bounds__(256) void k_pre(const float* __restrict__ slots, const float* __restrict__ g,
                                             const float* __restrict__ bbv, const float* __restrict__ M,
                                             float* __restrict__ qs){
  int row = blockIdx.x;      // 0..511 = b*8+i
  int t = threadIdx.x;
  __shared__ __align__(16) float sn[256];
  __shared__ float red[8];
  float v = slots[row*256 + t];
  float s = wredsum(v), ss = wredsum(v*v);
  int wid=t>>6, lane=t&63;
  if(lane==0){ red[wid]=s; red[4+wid]=ss; }
  __syncthreads();
  float S  = red[0]+red[1]+red[2]+red[3];
  float SS = red[4]+red[5]+red[6]+red[7];
  float m = S*(1.0f/256.0f);
  float r = rsqrtf(SS*(1.0f/256.0f) - m*m + 1e-5f);
  sn[t] = (v-m)*r*g[t]+bbv[t];
  __syncthreads();
  float a0=0.f, a1=0.f;
#pragma unroll 8
  for(int e=0;e<128;e++){
    a0 += sn[e]*M[e*256+t];
    a1 += sn[e+128]*M[(e+128)*256+t];
  }
  qs[row*256+t]=a0+a1;
}

// ---------------- pass1: dots + softmax(over slots) + eps -> w[b][j][8] ----------------
__global__ __launch_bounds__(256) void k_pass1(const __half* __restrict__ x, const float* __restrict__ qs,
                                               float* __restrict__ wbuf){
  int b = blockIdx.x>>4;                              // 16 blocks per batch
  size_t j = (size_t)blockIdx.x*256 + threadIdx.x;    // global row index (b*N + n)
  __shared__ __align__(16) float qt[256][8];          // qs transposed: [c][i]
  const float* qb = qs + b*2048;
  for(int e=threadIdx.x;e<2048;e+=256){ qt[e&255][e>>8]=qb[e]; }
  __syncthreads();
  const uint4* xr = (const uint4*)(x + j*DD);
  float pd[8]={0,0,0,0,0,0,0,0};
#pragma unroll 2
  for(int ch=0; ch<32; ch++){
    uint4 u = xr[ch];
    float2 f0=u2f2(u.x), f1=u2f2(u.y), f2=u2f2(u.z), f3=u2f2(u.w);
    float xv[8]={f0.x,f0.y,f1.x,f1.y,f2.x,f2.y,f3.x,f3.y};
    int c0=ch*8;
#pragma unroll
    for(int cc=0;cc<8;cc++){
      const float4* qp=(const float4*)&qt[c0+cc][0];
      float4 qa=qp[0], qc=qp[1];
      float xvv=xv[cc];
      pd[0]+=qa.x*xvv; pd[1]+=qa.y*xvv; pd[2]+=qa.z*xvv; pd[3]+=qa.w*xvv;
      pd[4]+=qc.x*xvv; pd[5]+=qc.y*xvv; pd[6]+=qc.z*xvv; pd[7]+=qc.w*xvv;
    }
  }
  float mx=pd[0];
#pragma unroll
  for(int i=1;i<8;i++) mx=fmaxf(mx,pd[i]);
  float ev[8]; float ssum=0.f;
#pragma unroll
  for(int i=0;i<8;i++){ ev[i]=__expf(pd[i]-mx); ssum+=ev[i]; }
  float inv=1.0f/ssum;
  float4 w0={ev[0]*inv+1e-5f, ev[1]*inv+1e-5f, ev[2]*inv+1e-5f, ev[3]*inv+1e-5f};
  float4 w1={ev[4]*inv+1e-5f, ev[5]*inv+1e-5f, ev[6]*inv+1e-5f, ev[7]*inv+1e-5f};
  float4* wp=(float4*)(wbuf + j*8);
  wp[0]=w0; wp[1]=w1;
}

// ---------------- pass2: partial agg[i][c] = sum_j w[i,j]*x[j,c], partial wsum ----------------
__global__ __launch_bounds__(256) void k_pass2(const __half* __restrict__ x, const float* __restrict__ wbuf,
                                               float* __restrict__ pagg){
  int b = blockIdx.x>>3, chnk = blockIdx.x&7;
  int jbase = chnk*512;
  __shared__ __align__(16) float wl[4096];         // 512 j * 8 i
  __shared__ __align__(16) float aggl[4][2048];
  __shared__ float wsl[4][8];
  const float* wsrc = wbuf + ((size_t)b*NN + jbase)*8;
  for(int e2=threadIdx.x;e2<4096;e2+=256) wl[e2]=wsrc[e2];
  __syncthreads();
  int wid=threadIdx.x>>6, lane=threadIdx.x&63;
  float acc[8][4];
#pragma unroll
  for(int i=0;i<8;i++){ acc[i][0]=0;acc[i][1]=0;acc[i][2]=0;acc[i][3]=0; }
  float ws[8]={0,0,0,0,0,0,0,0};
  const __half* xb = x + ((size_t)b*NN + jbase)*DD;
  for(int t2=0;t2<128;t2++){
    int jl = wid*128+t2;
    uint2 u = ((const uint2*)(xb + (size_t)jl*DD))[lane];
    float2 f01=u2f2(u.x), f23=u2f2(u.y);
    const float4* wp=(const float4*)&wl[jl*8];
    float4 wa=wp[0], wb_=wp[1];
    float wv[8]={wa.x,wa.y,wa.z,wa.w,wb_.x,wb_.y,wb_.z,wb_.w};
    float xv[4]={f01.x,f01.y,f23.x,f23.y};
#pragma unroll
    for(int i=0;i<8;i++){
      acc[i][0]+=wv[i]*xv[0]; acc[i][1]+=wv[i]*xv[1];
      acc[i][2]+=wv[i]*xv[2]; acc[i][3]+=wv[i]*xv[3];
      ws[i]+=wv[i];
    }
  }
#pragma unroll
  for(int i=0;i<8;i++){
    float4 st={acc[i][0],acc[i][1],acc[i][2],acc[i][3]};
    *((float4*)&aggl[wid][i*256 + lane*4])=st;
  }
  if(lane==0){
#pragma unroll
    for(int i=0;i<8;i++) wsl[wid][i]=ws[i];
  }
  __syncthreads();
  float* pb = pagg + (size_t)blockIdx.x*2064;
  for(int e2=threadIdx.x;e2<2048;e2+=256) pb[e2]=aggl[0][e2]+aggl[1][e2]+aggl[2][e2]+aggl[3][e2];
  if(threadIdx.x<8) pb[2048+threadIdx.x]=wsl[0][threadIdx.x]+wsl[1][threadIdx.x]+wsl[2][threadIdx.x]+wsl[3][threadIdx.x];
}

// ---------------- reduce partials + updates = (N/wsum)*agg @ Wv^T  (block = one (b,slot) row) ----------------
__global__ __launch_bounds__(256) void k_upd(const float* __restrict__ pagg, const float* __restrict__ WvT,
                                             float* __restrict__ upd){
  int bid=blockIdx.x;            // 0..511
  int b=bid>>3, i=bid&7, t=threadIdx.x;
  __shared__ float aggl[256];
  float s=0.f;
#pragma unroll
  for(int k=0;k<8;k++) s+=pagg[(size_t)(b*8+k)*2064 + i*256 + t];
  aggl[t]=s;
  float ws=0.f;
#pragma unroll
  for(int k=0;k<8;k++) ws+=pagg[(size_t)(b*8+k)*2064 + 2048 + i];
  float fac=4096.0f/ws;
  __syncthreads();
  float a0=0.f, a1=0.f;
#pragma unroll 8
  for(int c=0;c<128;c++){
    a0 += aggl[c]*WvT[c*256+t];
    a1 += aggl[c+128]*WvT[(c+128)*256+t];
  }
  upd[(size_t)bid*256 + t] = (a0+a1)*fac;
}

// ---------------- GRU gate GEMMs: gates[row][0:768]=upd@WihT+bih, [768:1536]=slots@WhhT+bhh ----------------
// block = (b, cg in 0..5, rh in 0..1): 4 rows x 256 cols per block
__global__ __launch_bounds__(256) void k_gates(const float* __restrict__ upd, const float* __restrict__ slots,
                                               const float* __restrict__ WihT, const float* __restrict__ WhhT,
                                               const float* __restrict__ bih, const float* __restrict__ bhh,
                                               float* __restrict__ gates){
  int blk=blockIdx.x;                 // 0..767
  int rh=blk&1, cg=(blk>>1)%6, b=blk/12;
  int t=threadIdx.x;
  bool isH = cg>=3;
  int col = (cg%3)*256 + t;           // 0..767
  const float* src  = (isH ? slots : upd) + (size_t)b*2048 + rh*1024;
  const float* WT   = isH ? WhhT : WihT;
  const float* bias = isH ? bhh  : bih;
  __shared__ float in[1024];
  for(int e=t;e<1024;e+=256) in[e]=src[e];
  __syncthreads();
  float a[4]={0,0,0,0};
#pragma unroll 8
  for(int c=0;c<256;c++){
    float w=WT[c*768+col];
#pragma unroll
    for(int k=0;k<4;k++) a[k]+=in[k*256+c]*w;
  }
  float bv=bias[col];
  size_t base=(size_t)(b*8+rh*4)*1536 + (isH?768:0) + col;
#pragma unroll
  for(int k=0;k<4;k++) gates[base + (size_t)k*1536] = a[k]+bv;
}

// ---------------- GRU nonlinearity + MLP pre-norm (fused) ----------------
__global__ __launch_bounds__(256) void k_gru_ln(const float* __restrict__ gates, const float* __restrict__ slots,
                                                const float* __restrict__ g, const float* __restrict__ bbv,
                                                float* __restrict__ h, float* __restrict__ ys){
  int row=blockIdx.x, t=threadIdx.x;
  const float* gr = gates + (size_t)row*1536;
  float gir=gr[t], giz=gr[256+t], gin=gr[512+t];
  float ghr=gr[768+t], ghz=gr[1024+t], ghn=gr[1280+t];
  float hp = slots[(size_t)row*256+t];
  float r = sigm(gir+ghr);
  float z = sigm(giz+ghz);
  float n = tanhf(gin + r*ghn);
  float hv = (1.0f-z)*n + z*hp;
  h[(size_t)row*256+t] = hv;
  // LayerNorm(hv) across the row
  float s=wredsum(hv), ss=wredsum(hv*hv);
  __shared__ float red[8];
  int wid=t>>6, lane=t&63;
  if(lane==0){ red[wid]=s; red[4+wid]=ss; }
  __syncthreads();
  float S=red[0]+red[1]+red[2]+red[3];
  float SS=red[4]+red[5]+red[6]+red[7];
  float m=S*(1.0f/256.0f);
  float rs=rsqrtf(SS*(1.0f/256.0f)-m*m+1e-5f);
  ys[(size_t)row*256+t]=(hv-m)*rs*g[t]+bbv[t];
}

// ---------------- MLP up-proj: z1 = leaky_relu(ys @ W1^T + b1)  [512,1024] ----------------
// block = (b, cb in 0..3, rh in 0..1): 4 rows x 256 cols
__global__ __launch_bounds__(256) void k_mlp1(const float* __restrict__ ys, const float* __restrict__ W1T,
                                              const float* __restrict__ b1, float* __restrict__ z1){
  int blk=blockIdx.x;                 // 0..511
  int rh=blk&1, cb=(blk>>1)&3, b=blk>>3;
  int t=threadIdx.x;
  int col=cb*256+t;                   // 0..1023
  __shared__ float in[1024];
  const float* src = ys + (size_t)b*2048 + rh*1024;
  for(int e=t;e<1024;e+=256) in[e]=src[e];
  __syncthreads();
  float a[4]={0,0,0,0};
#pragma unroll 8
  for(int c=0;c<256;c++){
    float w=W1T[c*1024+col];
#pragma unroll
    for(int k=0;k<4;k++) a[k]+=in[k*256+c]*w;
  }
  float bv=b1[col];
#pragma unroll
  for(int k=0;k<4;k++){
    float v=a[k]+bv; v = v>0.f ? v : 0.01f*v;
    z1[(size_t)(b*8+rh*4+k)*1024+col]=v;
  }
}

// ---------------- MLP down-proj + residual: out = h + z1 @ W2^T + b2  (block = one row) ----------------
__global__ __launch_bounds__(256) void k_mlp2(const float* __restrict__ z1, const float* __restrict__ h,
                                              const float* __restrict__ W2T, const float* __restrict__ b2,
                                              float* __restrict__ out){
  int row=blockIdx.x;                 // 0..511
  int t=threadIdx.x;
  __shared__ float zl[1024];
  const float* src = z1 + (size_t)row*1024;
  for(int e=t;e<1024;e+=256) zl[e]=src[e];
  __syncthreads();
  float a0=0.f, a1=0.f;
#pragma unroll 8
  for(int c=0;c<512;c++){
    a0 += zl[c]*W2T[c*256+t];
    a1 += zl[c+512]*W2T[(c+512)*256+t];
  }
  size_t o=(size_t)row*256+t;
  out[o]=h[o]+a0+a1+b2[t];
}

extern "C" void kernel_launch(void* const* d_in, const int* in_sizes, int n_in,
                              void* d_out, int out_size, void* d_ws, size_t ws_size,
                              hipStream_t stream){
  const float* inputs=(const float*)d_in[0];
  const float* sinit =(const float*)d_in[1];
  const float* Wq =(const float*)d_in[2];
  const float* Wk =(const float*)d_in[3];
  const float* Wv =(const float*)d_in[4];
  const float* Wih=(const float*)d_in[5];
  const float* Whh=(const float*)d_in[6];
  const float* bih=(const float*)d_in[7];
  const float* bhh=(const float*)d_in[8];
  const float* lin_g=(const float*)d_in[9];
  const float* lin_b=(const float*)d_in[10];
  const float* ls_g=(const float*)d_in[11];
  const float* ls_b=(const float*)d_in[12];
  const float* lm_g=(const float*)d_in[13];
  const float* lm_b=(const float*)d_in[14];
  const float* W1=(const float*)d_in[15];
  const float* b1=(const float*)d_in[16];
  const float* W2=(const float*)d_in[17];
  const float* b2=(const float*)d_in[18];

  char* w=(char*)d_ws;
  __half* x   =(__half*)w; w += (size_t)BB*NN*DD*2;         // 134.2 MB
  float* wbuf =(float*)w;  w += (size_t)BB*NN*NSL*4;        //   8.4 MB
  float* qs   =(float*)w;  w += 512*256*4;
  float* M    =(float*)w;  w += 256*256*4;
  float* WihT =(float*)w;  w += 768*256*4;
  float* WhhT =(float*)w;  w += 768*256*4;
  float* W1T  =(float*)w;  w += 1024*256*4;
  float* W2T  =(float*)w;  w += 1024*256*4;
  float* WvT  =(float*)w;  w += 256*256*4;
  float* slots=(float*)w;  w += 512*256*4;
  float* upd  =(float*)w;  w += 512*256*4;
  float* hb   =(float*)w;  w += 512*256*4;
  float* ysb  =(float*)w;  w += 512*256*4;
  float* gates=(float*)w;  w += (size_t)512*1536*4;
  float* z1   =(float*)w;  w += (size_t)512*1024*4;
  float* pagg =(float*)w;  w += (size_t)512*2064*4;

  hipLaunchKernelGGL(k_prep, dim3(1088), dim3(256), 0, stream,
                     Wih,Whh,W1,W2,Wv,sinit, WihT,WhhT,W1T,W2T,WvT,slots);
  hipLaunchKernelGGL(k_M,    dim3(256),  dim3(256), 0, stream, Wq, Wk, M);
  hipLaunchKernelGGL(k_ln_x, dim3(65536),dim3(256), 0, stream, inputs, lin_g, lin_b, x);
  for(int it=0; it<NITER; ++it){
    float* dst = (it==NITER-1) ? (float*)d_out : slots;
    hipLaunchKernelGGL(k_pre,    dim3(512), dim3(256), 0, stream, slots, ls_g, ls_b, M, qs);
    hipLaunchKernelGGL(k_pass1,  dim3(1024),dim3(256), 0, stream, x, qs, wbuf);
    hipLaunchKernelGGL(k_pass2,  dim3(512), dim3(256), 0, stream, x, wbuf, pagg);
    hipLaunchKernelGGL(k_upd,    dim3(512), dim3(256), 0, stream, pagg, WvT, upd);
    hipLaunchKernelGGL(k_gates,  dim3(768), dim3(256), 0, stream, upd, slots, WihT, WhhT, bih, bhh, gates);
    hipLaunchKernelGGL(k_gru_ln, dim3(512), dim3(256), 0, stream, gates, slots, lm_g, lm_b, hb, ysb);
    hipLaunchKernelGGL(k_mlp1,   dim3(512), dim3(256), 0, stream, ysb, W1T, b1, z1);
    hipLaunchKernelGGL(k_mlp2,   dim3(512), dim3(256), 0, stream, z1, hb, W2T, b2, dst);
  }
}

// Round 5
// 697.033 us; speedup vs baseline: 1.1227x; 1.1227x over previous
//
#include <hip/hip_runtime.h>
#include <hip/hip_fp16.h>
#include <hip/hip_bf16.h>

// SlotAttention restructured:
//  dots = qs . x   with qs = LN(slots) @ (scale * Wq^T Wk)   (K never materialized)
//  updates = (N/wsum) * (sum_j w_j x_j) @ Wv^T               (V never materialized)
// x = LN(inputs) stored once as fp16. All accumulation fp32. Output fp32.
// R4 (regressed): more blocks => more weight re-reads. R5: fuse pass1+pass2
// into k_att (x read once/iter, wbuf gone); fuse ENTIRE tail (upd,gates,gru,
// ln,mlp1,mlp2,next-pre) into k_tail: slot-rows are independent -> 128 blocks
// x 4 rows, intermediates in LDS (~61KB), weights streamed from L2 once/block.
// Dispatches 27 -> 10.

#define BB 64
#define NN 4096
#define DD 256
#define NSL 8
#define NITER 3

__device__ __forceinline__ float wredsum(float v){
#pragma unroll
  for(int m=32;m;m>>=1) v += __shfl_xor(v, m, 64);
  return v;
}
__device__ __forceinline__ float2 u2f2(unsigned u){ __half2 h; __builtin_memcpy(&h,&u,4); return __half22float2(h); }
__device__ __forceinline__ float sigm(float v){ return 1.0f/(1.0f+__expf(-v)); }

// ---------------- prep: weight transposes + slots broadcast init ----------------
__global__ __launch_bounds__(256) void k_prep(
    const float* __restrict__ Wih, const float* __restrict__ Whh,
    const float* __restrict__ W1,  const float* __restrict__ W2,
    const float* __restrict__ Wv,  const float* __restrict__ sinit,
    float* __restrict__ WihT, float* __restrict__ WhhT,
    float* __restrict__ W1T,  float* __restrict__ W2T,
    float* __restrict__ WvT,  float* __restrict__ slots){
  for(int idx = blockIdx.x*256 + threadIdx.x; idx < 1114112; idx += gridDim.x*256){
    if(idx < 196608){ int d=idx>>8, c=idx&255; WihT[c*768+d] = Wih[idx]; }
    else if(idx < 393216){ int k=idx-196608; int d=k>>8,  c=k&255;  WhhT[c*768+d]  = Whh[k]; }
    else if(idx < 655360){ int k=idx-393216; int d=k>>8,  c=k&255;  W1T[c*1024+d]  = W1[k]; }   // W1 [1024][256]
    else if(idx < 917504){ int k=idx-655360; int d=k>>10, c=k&1023; W2T[c*256+d]   = W2[k]; }   // W2 [256][1024]
    else if(idx < 983040){ int k=idx-917504; int d=k>>8,  c=k&255;  WvT[c*256+d]   = Wv[k]; }
    else { int k=idx-983040; slots[k] = sinit[k&2047]; }                                        // broadcast over b
  }
}

// ---------------- M = scale * Wq^T @ Wk  (M[e][c]) ----------------
__global__ __launch_bounds__(256) void k_M(const float* __restrict__ Wq, const float* __restrict__ Wk,
                                           float* __restrict__ M){
  int e = blockIdx.x, c = threadIdx.x;
  float acc = 0.f;
#pragma unroll 8
  for(int d=0; d<256; d++) acc += Wq[d*256+e]*Wk[d*256+c];
  M[e*256+c] = acc * 0.0625f;  // 256^-0.5
}

// ---------------- x = LN(inputs) -> fp16 ----------------
__global__ __launch_bounds__(256) void k_ln_x(const float* __restrict__ in, const float* __restrict__ g,
                                              const float* __restrict__ bbv, __half* __restrict__ x){
  int row  = blockIdx.x*4 + (threadIdx.x>>6);
  int lane = threadIdx.x&63;
  const float4 v = ((const float4*)(in + (size_t)row*DD))[lane];
  float s  = v.x+v.y+v.z+v.w;
  float ss = v.x*v.x+v.y*v.y+v.z*v.z+v.w*v.w;
  s = wredsum(s); ss = wredsum(ss);
  float m = s*(1.0f/256.0f);
  float r = rsqrtf(ss*(1.0f/256.0f) - m*m + 1e-5f);
  float4 gv = ((const float4*)g)[lane];
  float4 bv = ((const float4*)bbv)[lane];
  float y0=(v.x-m)*r*gv.x+bv.x, y1=(v.y-m)*r*gv.y+bv.y;
  float y2=(v.z-m)*r*gv.z+bv.z, y3=(v.w-m)*r*gv.w+bv.w;
  __half2 h0=__floats2half2_rn(y0,y1), h1=__floats2half2_rn(y2,y3);
  uint2 u; __builtin_memcpy(&u.x,&h0,4); __builtin_memcpy(&u.y,&h1,4);
  ((uint2*)(x + (size_t)row*DD))[lane] = u;
}

// ---------------- initial qs = LN(slots) @ M (once, before iter 0) ----------------
__global__ __launch_bounds__(256) void k_pre(const float* __restrict__ slots, const float* __restrict__ g,
                                             const float* __restrict__ bbv, const float* __restrict__ M,
                                             float* __restrict__ qs){
  int row = blockIdx.x;      // 0..511 = b*8+i
  int t = threadIdx.x;
  __shared__ __align__(16) float sn[256];
  __shared__ float red[8];
  float v = slots[row*256 + t];
  float s = wredsum(v), ss = wredsum(v*v);
  int wid=t>>6, lane=t&63;
  if(lane==0){ red[wid]=s; red[4+wid]=ss; }
  __syncthreads();
  float S  = red[0]+red[1]+red[2]+red[3];
  float SS = red[4]+red[5]+red[6]+red[7];
  float m = S*(1.0f/256.0f);
  float r = rsqrtf(SS*(1.0f/256.0f) - m*m + 1e-5f);
  sn[t] = (v-m)*r*g[t]+bbv[t];
  __syncthreads();
  float a0=0.f, a1=0.f;
#pragma unroll 8
  for(int e=0;e<128;e++){
    a0 += sn[e]*M[e*256+t];
    a1 += sn[e+128]*M[(e+128)*256+t];
  }
  qs[row*256+t]=a0+a1;
}

// ---------------- fused attention pass: dots+softmax+eps -> w (LDS) -> partial agg ----------------
// grid 1024 (16 blocks/batch, 256 j-rows each), 256 threads
__global__ __launch_bounds__(256) void k_att(const __half* __restrict__ x, const float* __restrict__ qs,
                                             float* __restrict__ pagg){
  int b = blockIdx.x>>4;
  int t = threadIdx.x;
  size_t j = (size_t)blockIdx.x*256 + t;
  __shared__ __align__(16) float qt[256][8];     // qs transposed [c][i]
  __shared__ __align__(16) float wl[256][8];     // softmax weights per row
  __shared__ __align__(16) float aggl[4][2048];
  __shared__ float wsl[4][8];
  const float* qb = qs + b*2048;
  for(int e=t;e<2048;e+=256) qt[e&255][e>>8]=qb[e];
  __syncthreads();
  // phase 1: dots + softmax over slots
  const uint4* xr = (const uint4*)(x + j*DD);
  float pd[8]={0,0,0,0,0,0,0,0};
#pragma unroll 2
  for(int ch=0; ch<32; ch++){
    uint4 u = xr[ch];
    float2 f0=u2f2(u.x), f1=u2f2(u.y), f2=u2f2(u.z), f3=u2f2(u.w);
    float xv[8]={f0.x,f0.y,f1.x,f1.y,f2.x,f2.y,f3.x,f3.y};
    int c0=ch*8;
#pragma unroll
    for(int cc=0;cc<8;cc++){
      const float4* qp=(const float4*)&qt[c0+cc][0];
      float4 qa=qp[0], qc=qp[1];
      float xvv=xv[cc];
      pd[0]+=qa.x*xvv; pd[1]+=qa.y*xvv; pd[2]+=qa.z*xvv; pd[3]+=qa.w*xvv;
      pd[4]+=qc.x*xvv; pd[5]+=qc.y*xvv; pd[6]+=qc.z*xvv; pd[7]+=qc.w*xvv;
    }
  }
  float mx=pd[0];
#pragma unroll
  for(int i=1;i<8;i++) mx=fmaxf(mx,pd[i]);
  float ev[8]; float ssum=0.f;
#pragma unroll
  for(int i=0;i<8;i++){ ev[i]=__expf(pd[i]-mx); ssum+=ev[i]; }
  float inv=1.0f/ssum;
#pragma unroll
  for(int i=0;i<8;i++) wl[t][i]=ev[i]*inv+1e-5f;
  __syncthreads();
  // phase 2: agg[i][c] += w[i,j]*x[j,c] over this block's 256 rows (re-read hits L2)
  int wid=t>>6, lane=t&63;
  float acc[8][4];
#pragma unroll
  for(int i=0;i<8;i++){ acc[i][0]=0;acc[i][1]=0;acc[i][2]=0;acc[i][3]=0; }
  float ws[8]={0,0,0,0,0,0,0,0};
  for(int r=0;r<64;r++){
    int jl = wid*64 + r;
    uint2 u = ((const uint2*)(x + ((size_t)blockIdx.x*256 + jl)*DD))[lane];
    float2 f01=u2f2(u.x), f23=u2f2(u.y);
    const float4* wp=(const float4*)&wl[jl][0];
    float4 wa=wp[0], wb_=wp[1];
    float wv[8]={wa.x,wa.y,wa.z,wa.w,wb_.x,wb_.y,wb_.z,wb_.w};
    float xv[4]={f01.x,f01.y,f23.x,f23.y};
#pragma unroll
    for(int i=0;i<8;i++){
      acc[i][0]+=wv[i]*xv[0]; acc[i][1]+=wv[i]*xv[1];
      acc[i][2]+=wv[i]*xv[2]; acc[i][3]+=wv[i]*xv[3];
      ws[i]+=wv[i];
    }
  }
#pragma unroll
  for(int i=0;i<8;i++){
    float4 st={acc[i][0],acc[i][1],acc[i][2],acc[i][3]};
    *((float4*)&aggl[wid][i*256 + lane*4])=st;
  }
  if(lane==0){
#pragma unroll
    for(int i=0;i<8;i++) wsl[wid][i]=ws[i];
  }
  __syncthreads();
  float* pb = pagg + (size_t)blockIdx.x*2064;
  for(int e=t;e<2048;e+=256) pb[e]=aggl[0][e]+aggl[1][e]+aggl[2][e]+aggl[3][e];
  if(t<8) pb[2048+t]=wsl[0][t]+wsl[1][t]+wsl[2][t]+wsl[3][t];
}

// ---------------- fused tail: upd -> gates -> GRU -> LN -> MLP -> (slot-LN + qs) ----------------
// grid 128 (2 blocks/batch, 4 slot-rows each), 512 threads. All intermediates in LDS.
__global__ __launch_bounds__(512,1) void k_tail(
    const float* __restrict__ pagg, const float* __restrict__ WvT,
    const float* __restrict__ slots_in,
    const float* __restrict__ WihT, const float* __restrict__ WhhT,
    const float* __restrict__ bih, const float* __restrict__ bhh,
    const float* __restrict__ lm_g, const float* __restrict__ lm_b,
    const float* __restrict__ W1T, const float* __restrict__ b1,
    const float* __restrict__ W2T, const float* __restrict__ b2,
    const float* __restrict__ ls_g, const float* __restrict__ ls_b,
    const float* __restrict__ M,
    float* __restrict__ slots_out, float* __restrict__ qs_out, int last){
  int blk=blockIdx.x;        // 0..127
  int b=blk>>1, rh=blk&1;
  int t=threadIdx.x;
  int lane=t&63, wid=t>>6;
  __shared__ float sb[1024], updl[1024], hl[1024], ysl[1024], snl[1024];
  __shared__ float gl[4*1536];
  __shared__ float z1l[4*1024];   // first 1024 floats double as agg in phase A
  __shared__ float fac[4];
  __shared__ float redS[4][4], redQ[4][4];
  float* const agg = z1l;

  const float* pb = pagg + (size_t)b*16*2064;
  int roff = rh*4;
  // ---- A: reduce pagg chunks + load slots; upd GEMM
  for(int e=t;e<1024;e+=512){
    float s=0.f;
#pragma unroll
    for(int k2=0;k2<16;k2++) s += pb[k2*2064 + roff*256 + e];
    agg[e]=s;
    sb[e]=slots_in[(size_t)b*2048 + roff*256 + e];
  }
  if(t<4){
    float s=0.f;
#pragma unroll
    for(int k2=0;k2<16;k2++) s += pb[k2*2064 + 2048 + roff + t];
    fac[t]=4096.0f/s;
  }
  __syncthreads();
  {
    int r0=t>>8, col=t&255;      // rows r0 and r0+2
    float a0=0.f,a1=0.f;
#pragma unroll 8
    for(int c=0;c<256;c++){
      float w=WvT[c*256+col];
      a0+=agg[r0*256+c]*w; a1+=agg[(r0+2)*256+c]*w;
    }
    updl[r0*256+col]=a0*fac[r0];
    updl[(r0+2)*256+col]=a1*fac[r0+2];
  }
  __syncthreads();
  // ---- B: gate GEMMs (cols 0..767 = ih, 768..1535 = hh); wave-aligned splits
  for(int cc=0;cc<3;cc++){
    int col=cc*512+t;
    bool isH = col>=768;
    int wcol = isH? col-768 : col;
    const float* WT = isH? WhhT : WihT;
    const float* inb = isH? sb : updl;
    float a0=0.f,a1=0.f,a2=0.f,a3=0.f;
#pragma unroll 8
    for(int c=0;c<256;c++){
      float w=WT[c*768+wcol];
      a0+=inb[c]*w; a1+=inb[256+c]*w; a2+=inb[512+c]*w; a3+=inb[768+c]*w;
    }
    float bv = isH? bhh[wcol] : bih[wcol];
    gl[col]=a0+bv; gl[1536+col]=a1+bv; gl[3072+col]=a2+bv; gl[4608+col]=a3+bv;
  }
  __syncthreads();
  // ---- C: GRU nonlinearity + mlp pre-norm
  for(int rp=0;rp<2;rp++){
    int row = rp*2 + (t>>8);
    int cl = t&255;
    const float* gr=&gl[row*1536];
    float gir=gr[cl], giz=gr[256+cl], gin=gr[512+cl];
    float ghr=gr[768+cl], ghz=gr[1024+cl], ghn=gr[1280+cl];
    float hp = sb[row*256+cl];
    float r=sigm(gir+ghr), z=sigm(giz+ghz);
    float n=tanhf(gin + r*ghn);
    float hv=(1.0f-z)*n + z*hp;
    hl[row*256+cl]=hv;
    float s=wredsum(hv), ss=wredsum(hv*hv);
    if(lane==0){ redS[row][wid&3]=s; redQ[row][wid&3]=ss; }
  }
  __syncthreads();
  for(int rp=0;rp<2;rp++){
    int row = rp*2 + (t>>8);
    int cl = t&255;
    float S =redS[row][0]+redS[row][1]+redS[row][2]+redS[row][3];
    float SS=redQ[row][0]+redQ[row][1]+redQ[row][2]+redQ[row][3];
    float m=S*(1.0f/256.0f);
    float rs=rsqrtf(SS*(1.0f/256.0f)-m*m+1e-5f);
    ysl[row*256+cl]=(hl[row*256+cl]-m)*rs*lm_g[cl]+lm_b[cl];
  }
  __syncthreads();
  // ---- D: mlp up-proj + leaky relu  (overwrites z1l/agg)
  for(int cc=0;cc<2;cc++){
    int col=cc*512+t;
    float a0=0.f,a1=0.f,a2=0.f,a3=0.f;
#pragma unroll 8
    for(int c=0;c<256;c++){
      float w=W1T[c*1024+col];
      a0+=ysl[c]*w; a1+=ysl[256+c]*w; a2+=ysl[512+c]*w; a3+=ysl[768+c]*w;
    }
    float bv=b1[col];
    a0+=bv; a1+=bv; a2+=bv; a3+=bv;
    z1l[col]     = a0>0.f?a0:0.01f*a0;
    z1l[1024+col]= a1>0.f?a1:0.01f*a1;
    z1l[2048+col]= a2>0.f?a2:0.01f*a2;
    z1l[3072+col]= a3>0.f?a3:0.01f*a3;
  }
  __syncthreads();
  // ---- E: mlp down-proj + residual; write slots
  {
    int r0=t>>8, col=t&255;
    float a0=0.f,a1=0.f;
#pragma unroll 8
    for(int c=0;c<1024;c++){
      float w=W2T[c*256+col];
      a0+=z1l[r0*1024+c]*w; a1+=z1l[(r0+2)*1024+c]*w;
    }
    float bv=b2[col];
    float s0=hl[r0*256+col]+a0+bv;
    float s1=hl[(r0+2)*256+col]+a1+bv;
    snl[r0*256+col]=s0; snl[(r0+2)*256+col]=s1;
    slots_out[(size_t)b*2048 + (roff+r0)*256 + col]=s0;
    slots_out[(size_t)b*2048 + (roff+r0+2)*256 + col]=s1;
  }
  if(last) return;
  __syncthreads();
  // ---- F: slot-LN + qs for next iteration
  for(int rp=0;rp<2;rp++){
    int row=rp*2+(t>>8), cl=t&255;
    float v=snl[row*256+cl];
    float s=wredsum(v), ss=wredsum(v*v);
    if(lane==0){ redS[row][wid&3]=s; redQ[row][wid&3]=ss; }
  }
  __syncthreads();
  for(int rp=0;rp<2;rp++){
    int row=rp*2+(t>>8), cl=t&255;
    float S =redS[row][0]+redS[row][1]+redS[row][2]+redS[row][3];
    float SS=redQ[row][0]+redQ[row][1]+redQ[row][2]+redQ[row][3];
    float m=S*(1.0f/256.0f);
    float rs=rsqrtf(SS*(1.0f/256.0f)-m*m+1e-5f);
    ysl[row*256+cl]=(snl[row*256+cl]-m)*rs*ls_g[cl]+ls_b[cl];
  }
  __syncthreads();
  {
    int r0=t>>8, col=t&255;
    float a0=0.f,a1=0.f;
#pragma unroll 8
    for(int c=0;c<256;c++){
      float w=M[c*256+col];
      a0+=ysl[r0*256+c]*w; a1+=ysl[(r0+2)*256+c]*w;
    }
    qs_out[(size_t)b*2048 + (roff+r0)*256+col]=a0;
    qs_out[(size_t)b*2048 + (roff+r0+2)*256+col]=a1;
  }
}

extern "C" void kernel_launch(void* const* d_in, const int* in_sizes, int n_in,
                              void* d_out, int out_size, void* d_ws, size_t ws_size,
                              hipStream_t stream){
  const float* inputs=(const float*)d_in[0];
  const float* sinit =(const float*)d_in[1];
  const float* Wq =(const float*)d_in[2];
  const float* Wk =(const float*)d_in[3];
  const float* Wv =(const float*)d_in[4];
  const float* Wih=(const float*)d_in[5];
  const float* Whh=(const float*)d_in[6];
  const float* bih=(const float*)d_in[7];
  const float* bhh=(const float*)d_in[8];
  const float* lin_g=(const float*)d_in[9];
  const float* lin_b=(const float*)d_in[10];
  const float* ls_g=(const float*)d_in[11];
  const float* ls_b=(const float*)d_in[12];
  const float* lm_g=(const float*)d_in[13];
  const float* lm_b=(const float*)d_in[14];
  const float* W1=(const float*)d_in[15];
  const float* b1=(const float*)d_in[16];
  const float* W2=(const float*)d_in[17];
  const float* b2=(const float*)d_in[18];

  char* w=(char*)d_ws;
  __half* x   =(__half*)w; w += (size_t)BB*NN*DD*2;         // 134.2 MB
  float* qs   =(float*)w;  w += 512*256*4;
  float* M    =(float*)w;  w += 256*256*4;
  float* WihT =(float*)w;  w += 768*256*4;
  float* WhhT =(float*)w;  w += 768*256*4;
  float* W1T  =(float*)w;  w += 1024*256*4;
  float* W2T  =(float*)w;  w += 1024*256*4;
  float* WvT  =(float*)w;  w += 256*256*4;
  float* slots=(float*)w;  w += 512*256*4;
  float* pagg =(float*)w;  w += (size_t)1024*2064*4;        // 8.45 MB

  hipLaunchKernelGGL(k_prep, dim3(1088), dim3(256), 0, stream,
                     Wih,Whh,W1,W2,Wv,sinit, WihT,WhhT,W1T,W2T,WvT,slots);
  hipLaunchKernelGGL(k_M,    dim3(256),  dim3(256), 0, stream, Wq, Wk, M);
  hipLaunchKernelGGL(k_ln_x, dim3(65536),dim3(256), 0, stream, inputs, lin_g, lin_b, x);
  hipLaunchKernelGGL(k_pre,  dim3(512),  dim3(256), 0, stream, slots, ls_g, ls_b, M, qs);
  for(int it=0; it<NITER; ++it){
    int last = (it==NITER-1);
    float* dst = last ? (float*)d_out : slots;
    hipLaunchKernelGGL(k_att,  dim3(1024), dim3(256), 0, stream, x, qs, pagg);
    hipLaunchKernelGGL(k_tail, dim3(128),  dim3(512), 0, stream,
                       pagg, WvT, slots, WihT, WhhT, bih, bhh,
                       lm_g, lm_b, W1T, b1, W2T, b2, ls_g, ls_b, M,
                       dst, qs, last);
  }
}

// Round 6
// 479.346 us; speedup vs baseline: 1.6325x; 1.4541x over previous
//
#include <hip/hip_runtime.h>
#include <hip/hip_fp16.h>
#include <hip/hip_bf16.h>

// SlotAttention restructured:
//  dots = qs . x   with qs = LN(slots) @ (scale * Wq^T Wk)   (K never materialized)
//  updates = (N/wsum) * (sum_j w_j x_j) @ Wv^T               (V never materialized)
// x = LN(inputs) stored once as fp16. All accumulation fp32. Output fp32.
// R5: k_tail 178us/call, latency-bound (grid 128 = half GPU idle; scalar fp32
// transposed-weight loads). R6: fp16 weights in ORIGINAL [col][K] layout,
// streamed per-thread as uint4 (8 halves); grid 256 x 512thr, 2 rows/block;
// K-split with LDS combine for 256-col phases.

#define BB 64
#define NN 4096
#define DD 256
#define NSL 8
#define NITER 3

__device__ __forceinline__ float wredsum(float v){
#pragma unroll
  for(int m=32;m;m>>=1) v += __shfl_xor(v, m, 64);
  return v;
}
__device__ __forceinline__ float2 u2f2(unsigned u){ __half2 h; __builtin_memcpy(&h,&u,4); return __half22float2(h); }
__device__ __forceinline__ float sigm(float v){ return 1.0f/(1.0f+__expf(-v)); }
__device__ __forceinline__ void up8(uint4 u, float* w){
  float2 f;
  f=u2f2(u.x); w[0]=f.x; w[1]=f.y;
  f=u2f2(u.y); w[2]=f.x; w[3]=f.y;
  f=u2f2(u.z); w[4]=f.x; w[5]=f.y;
  f=u2f2(u.w); w[6]=f.x; w[7]=f.y;
}

// ---------------- prep: fp16 weight casts (original layout) + slots broadcast ----------------
__global__ __launch_bounds__(256) void k_prep(
    const float* __restrict__ Wih, const float* __restrict__ Whh,
    const float* __restrict__ W1,  const float* __restrict__ W2,
    const float* __restrict__ Wv,  const float* __restrict__ sinit,
    __half* __restrict__ Wihh, __half* __restrict__ Whhh,
    __half* __restrict__ W1h,  __half* __restrict__ W2h,
    __half* __restrict__ Wvh,  float* __restrict__ slots){
  for(int idx = blockIdx.x*256 + threadIdx.x; idx < 1114112; idx += gridDim.x*256){
    if(idx < 196608) Wihh[idx] = __float2half(Wih[idx]);
    else if(idx < 393216){ int k=idx-196608; Whhh[k]=__float2half(Whh[k]); }
    else if(idx < 655360){ int k=idx-393216; W1h[k]=__float2half(W1[k]); }
    else if(idx < 917504){ int k=idx-655360; W2h[k]=__float2half(W2[k]); }
    else if(idx < 983040){ int k=idx-917504; Wvh[k]=__float2half(Wv[k]); }
    else { int k=idx-983040; slots[k] = sinit[k&2047]; }
  }
}

// ---------------- M2[c][e] = scale * (Wq^T Wk)[e][c]  (fp16, per-out-col rows) ----------------
__global__ __launch_bounds__(256) void k_M(const float* __restrict__ Wq, const float* __restrict__ Wk,
                                           __half* __restrict__ M2h){
  int c = blockIdx.x, e = threadIdx.x;
  float acc = 0.f;
#pragma unroll 8
  for(int d=0; d<256; d++) acc += Wq[d*256+e]*Wk[d*256+c];
  M2h[c*256+e] = __float2half(acc * 0.0625f);  // 256^-0.5
}

// ---------------- x = LN(inputs) -> fp16 ----------------
__global__ __launch_bounds__(256) void k_ln_x(const float* __restrict__ in, const float* __restrict__ g,
                                              const float* __restrict__ bbv, __half* __restrict__ x){
  int row  = blockIdx.x*4 + (threadIdx.x>>6);
  int lane = threadIdx.x&63;
  const float4 v = ((const float4*)(in + (size_t)row*DD))[lane];
  float s  = v.x+v.y+v.z+v.w;
  float ss = v.x*v.x+v.y*v.y+v.z*v.z+v.w*v.w;
  s = wredsum(s); ss = wredsum(ss);
  float m = s*(1.0f/256.0f);
  float r = rsqrtf(ss*(1.0f/256.0f) - m*m + 1e-5f);
  float4 gv = ((const float4*)g)[lane];
  float4 bv = ((const float4*)bbv)[lane];
  float y0=(v.x-m)*r*gv.x+bv.x, y1=(v.y-m)*r*gv.y+bv.y;
  float y2=(v.z-m)*r*gv.z+bv.z, y3=(v.w-m)*r*gv.w+bv.w;
  __half2 h0=__floats2half2_rn(y0,y1), h1=__floats2half2_rn(y2,y3);
  uint2 u; __builtin_memcpy(&u.x,&h0,4); __builtin_memcpy(&u.y,&h1,4);
  ((uint2*)(x + (size_t)row*DD))[lane] = u;
}

// ---------------- initial qs = LN(slots) @ M (once, before iter 0) ----------------
__global__ __launch_bounds__(256) void k_pre(const float* __restrict__ slots, const float* __restrict__ g,
                                             const float* __restrict__ bbv, const __half* __restrict__ M2h,
                                             float* __restrict__ qs){
  int row = blockIdx.x;      // 0..511 = b*8+i
  int t = threadIdx.x;
  __shared__ __align__(16) float sn[256];
  __shared__ float red[8];
  float v = slots[row*256 + t];
  float s = wredsum(v), ss = wredsum(v*v);
  int wid=t>>6, lane=t&63;
  if(lane==0){ red[wid]=s; red[4+wid]=ss; }
  __syncthreads();
  float S  = red[0]+red[1]+red[2]+red[3];
  float SS = red[4]+red[5]+red[6]+red[7];
  float m = S*(1.0f/256.0f);
  float r = rsqrtf(SS*(1.0f/256.0f) - m*m + 1e-5f);
  sn[t] = (v-m)*r*g[t]+bbv[t];
  __syncthreads();
  const uint4* w4 = (const uint4*)(M2h + (size_t)t*256);
  float acc=0.f;
#pragma unroll 4
  for(int kk=0;kk<32;kk++){
    uint4 u=w4[kk]; float w[8]; up8(u,w);
#pragma unroll
    for(int j=0;j<8;j++) acc += sn[kk*8+j]*w[j];
  }
  qs[row*256+t]=acc;
}

// ---------------- fused attention pass: dots+softmax+eps -> w (LDS) -> partial agg ----------------
// grid 1024 (16 blocks/batch, 256 j-rows each), 256 threads
__global__ __launch_bounds__(256) void k_att(const __half* __restrict__ x, const float* __restrict__ qs,
                                             float* __restrict__ pagg){
  int b = blockIdx.x>>4;
  int t = threadIdx.x;
  size_t j = (size_t)blockIdx.x*256 + t;
  __shared__ __align__(16) float qt[256][8];     // qs transposed [c][i]
  __shared__ __align__(16) float wl[256][8];     // softmax weights per row
  __shared__ __align__(16) float aggl[4][2048];
  __shared__ float wsl[4][8];
  const float* qb = qs + b*2048;
  for(int e=t;e<2048;e+=256) qt[e&255][e>>8]=qb[e];
  __syncthreads();
  // phase 1: dots + softmax over slots
  const uint4* xr = (const uint4*)(x + j*DD);
  float pd[8]={0,0,0,0,0,0,0,0};
#pragma unroll 2
  for(int ch=0; ch<32; ch++){
    uint4 u = xr[ch];
    float2 f0=u2f2(u.x), f1=u2f2(u.y), f2=u2f2(u.z), f3=u2f2(u.w);
    float xv[8]={f0.x,f0.y,f1.x,f1.y,f2.x,f2.y,f3.x,f3.y};
    int c0=ch*8;
#pragma unroll
    for(int cc=0;cc<8;cc++){
      const float4* qp=(const float4*)&qt[c0+cc][0];
      float4 qa=qp[0], qc=qp[1];
      float xvv=xv[cc];
      pd[0]+=qa.x*xvv; pd[1]+=qa.y*xvv; pd[2]+=qa.z*xvv; pd[3]+=qa.w*xvv;
      pd[4]+=qc.x*xvv; pd[5]+=qc.y*xvv; pd[6]+=qc.z*xvv; pd[7]+=qc.w*xvv;
    }
  }
  float mx=pd[0];
#pragma unroll
  for(int i=1;i<8;i++) mx=fmaxf(mx,pd[i]);
  float ev[8]; float ssum=0.f;
#pragma unroll
  for(int i=0;i<8;i++){ ev[i]=__expf(pd[i]-mx); ssum+=ev[i]; }
  float inv=1.0f/ssum;
#pragma unroll
  for(int i=0;i<8;i++) wl[t][i]=ev[i]*inv+1e-5f;
  __syncthreads();
  // phase 2: agg[i][c] += w[i,j]*x[j,c] over this block's 256 rows (re-read hits L2)
  int wid=t>>6, lane=t&63;
  float acc[8][4];
#pragma unroll
  for(int i=0;i<8;i++){ acc[i][0]=0;acc[i][1]=0;acc[i][2]=0;acc[i][3]=0; }
  float ws[8]={0,0,0,0,0,0,0,0};
  for(int r=0;r<64;r++){
    int jl = wid*64 + r;
    uint2 u = ((const uint2*)(x + ((size_t)blockIdx.x*256 + jl)*DD))[lane];
    float2 f01=u2f2(u.x), f23=u2f2(u.y);
    const float4* wp=(const float4*)&wl[jl][0];
    float4 wa=wp[0], wb_=wp[1];
    float wv[8]={wa.x,wa.y,wa.z,wa.w,wb_.x,wb_.y,wb_.z,wb_.w};
    float xv[4]={f01.x,f01.y,f23.x,f23.y};
#pragma unroll
    for(int i=0;i<8;i++){
      acc[i][0]+=wv[i]*xv[0]; acc[i][1]+=wv[i]*xv[1];
      acc[i][2]+=wv[i]*xv[2]; acc[i][3]+=wv[i]*xv[3];
      ws[i]+=wv[i];
    }
  }
#pragma unroll
  for(int i=0;i<8;i++){
    float4 st={acc[i][0],acc[i][1],acc[i][2],acc[i][3]};
    *((float4*)&aggl[wid][i*256 + lane*4])=st;
  }
  if(lane==0){
#pragma unroll
    for(int i=0;i<8;i++) wsl[wid][i]=ws[i];
  }
  __syncthreads();
  float* pb = pagg + (size_t)blockIdx.x*2064;
  for(int e=t;e<2048;e+=256) pb[e]=aggl[0][e]+aggl[1][e]+aggl[2][e]+aggl[3][e];
  if(t<8) pb[2048+t]=wsl[0][t]+wsl[1][t]+wsl[2][t]+wsl[3][t];
}

// ---------------- fused tail v2: upd -> gates -> GRU -> LN -> MLP -> (slot-LN + qs) ----------------
// grid 256 (4 blocks/batch, 2 slot-rows each), 512 threads. fp16 weights streamed uint4 per-col.
__global__ __launch_bounds__(512) void k_tail(
    const float* __restrict__ pagg, const __half* __restrict__ Wvh,
    const float* __restrict__ slots_in,
    const __half* __restrict__ Wihh, const __half* __restrict__ Whhh,
    const float* __restrict__ bih, const float* __restrict__ bhh,
    const float* __restrict__ lm_g, const float* __restrict__ lm_b,
    const __half* __restrict__ W1h, const float* __restrict__ b1,
    const __half* __restrict__ W2h, const float* __restrict__ b2,
    const float* __restrict__ ls_g, const float* __restrict__ ls_b,
    const __half* __restrict__ M2h,
    float* __restrict__ slots_out, float* __restrict__ qs_out, int last){
  int blk=blockIdx.x;            // 0..255
  int b=blk>>2, rq=blk&3;        // rows rq*2, rq*2+1 (global slot rows b*8+roff+r)
  int t=threadIdx.x;
  int lane=t&63, wid=t>>6;
  int roff=rq*2;
  __shared__ float sb[512], updl[512], hl[512], ysl[512], snl[512], agg[512];
  __shared__ float gl[2*1536];
  __shared__ float z1l[2*1024];
  __shared__ float pp[2][2][256];
  __shared__ float fac[2];
  __shared__ float redS[2][4], redQ[2][4];

  const float* pb = pagg + (size_t)b*16*2064;
  // ---- A0: reduce pagg partials + load slots
  {
    float s=0.f;
#pragma unroll
    for(int k2=0;k2<16;k2++) s += pb[k2*2064 + roff*256 + t];
    agg[t]=s;
    sb[t]=slots_in[(size_t)b*2048 + roff*256 + t];
  }
  if(t<2){
    float s=0.f;
#pragma unroll
    for(int k2=0;k2<16;k2++) s += pb[k2*2064 + 2048 + roff + t];
    fac[t]=4096.0f/s;
  }
  __syncthreads();
  // ---- A1: upd = (agg @ Wv^T)*fac ; col=t&255, K split by t>>8
  {
    int col=t&255, kh=t>>8;
    const uint4* w4 = (const uint4*)(Wvh + (size_t)col*256 + kh*128);
    float a0=0.f,a1=0.f;
#pragma unroll 4
    for(int kk=0;kk<16;kk++){
      uint4 u=w4[kk]; float w[8]; up8(u,w);
      int kb=kh*128+kk*8;
#pragma unroll
      for(int j=0;j<8;j++){ a0+=agg[kb+j]*w[j]; a1+=agg[256+kb+j]*w[j]; }
    }
    pp[kh][0][col]=a0; pp[kh][1][col]=a1;
  }
  __syncthreads();
  {
    int col=t&255, r=t>>8;
    updl[r*256+col] = (pp[0][r][col]+pp[1][r][col])*fac[r];
  }
  __syncthreads();
  // ---- B: gate GEMMs, 3 chunks of 512 cols (0..767 ih from upd, 768..1535 hh from slots)
  for(int ch=0; ch<3; ch++){
    int col = ch*512 + t;
    const __half* wr; const float* inb; float bv;
    if(col<768){ wr=Wihh + (size_t)col*256; inb=updl; bv=bih[col]; }
    else       { wr=Whhh + (size_t)(col-768)*256; inb=sb; bv=bhh[col-768]; }
    const uint4* w4=(const uint4*)wr;
    float a0=0.f,a1=0.f;
#pragma unroll 4
    for(int kk=0;kk<32;kk++){
      uint4 u=w4[kk]; float w[8]; up8(u,w);
      int kb=kk*8;
#pragma unroll
      for(int j=0;j<8;j++){ a0+=inb[kb+j]*w[j]; a1+=inb[256+kb+j]*w[j]; }
    }
    gl[col]=a0+bv; gl[1536+col]=a1+bv;
  }
  __syncthreads();
  // ---- C: GRU nonlinearity + MLP pre-norm
  {
    int r=t>>8, cl=t&255;
    const float* gr=&gl[r*1536];
    float gir=gr[cl], giz=gr[256+cl], gin=gr[512+cl];
    float ghr=gr[768+cl], ghz=gr[1024+cl], ghn=gr[1280+cl];
    float hp = sb[r*256+cl];
    float rr=sigm(gir+ghr), z=sigm(giz+ghz);
    float n=tanhf(gin + rr*ghn);
    float hv=(1.0f-z)*n + z*hp;
    hl[r*256+cl]=hv;
    float s=wredsum(hv), ss=wredsum(hv*hv);
    if(lane==0){ redS[r][wid&3]=s; redQ[r][wid&3]=ss; }
  }
  __syncthreads();
  {
    int r=t>>8, cl=t&255;
    float S =redS[r][0]+redS[r][1]+redS[r][2]+redS[r][3];
    float SS=redQ[r][0]+redQ[r][1]+redQ[r][2]+redQ[r][3];
    float m=S*(1.0f/256.0f);
    float rs=rsqrtf(SS*(1.0f/256.0f)-m*m+1e-5f);
    ysl[r*256+cl]=(hl[r*256+cl]-m)*rs*lm_g[cl]+lm_b[cl];
  }
  __syncthreads();
  // ---- D: mlp up-proj + leaky relu, 2 chunks of 512 cols
  for(int ch=0;ch<2;ch++){
    int col=ch*512+t;
    const uint4* w4=(const uint4*)(W1h + (size_t)col*256);
    float a0=0.f,a1=0.f;
#pragma unroll 4
    for(int kk=0;kk<32;kk++){
      uint4 u=w4[kk]; float w[8]; up8(u,w);
      int kb=kk*8;
#pragma unroll
      for(int j=0;j<8;j++){ a0+=ysl[kb+j]*w[j]; a1+=ysl[256+kb+j]*w[j]; }
    }
    float bv=b1[col];
    a0+=bv; a1+=bv;
    z1l[col]      = a0>0.f?a0:0.01f*a0;
    z1l[1024+col] = a1>0.f?a1:0.01f*a1;
  }
  __syncthreads();
  // ---- E: mlp down-proj (K=1024 split 512/512) + residual; write slots
  {
    int col=t&255, kh=t>>8;
    const uint4* w4=(const uint4*)(W2h + (size_t)col*1024 + kh*512);
    float a0=0.f,a1=0.f;
#pragma unroll 4
    for(int kk=0;kk<64;kk++){
      uint4 u=w4[kk]; float w[8]; up8(u,w);
      int kb=kh*512+kk*8;
#pragma unroll
      for(int j=0;j<8;j++){ a0+=z1l[kb+j]*w[j]; a1+=z1l[1024+kb+j]*w[j]; }
    }
    pp[kh][0][col]=a0; pp[kh][1][col]=a1;
  }
  __syncthreads();
  {
    int col=t&255, r=t>>8;
    float v = hl[r*256+col] + pp[0][r][col]+pp[1][r][col] + b2[col];
    snl[r*256+col]=v;
    slots_out[(size_t)b*2048 + (roff+r)*256 + col]=v;
  }
  if(last) return;
  __syncthreads();
  // ---- F: slot-LN + qs for next iteration
  {
    int r=t>>8, cl=t&255;
    float v=snl[r*256+cl];
    float s=wredsum(v), ss=wredsum(v*v);
    if(lane==0){ redS[r][wid&3]=s; redQ[r][wid&3]=ss; }
  }
  __syncthreads();
  {
    int r=t>>8, cl=t&255;
    float S =redS[r][0]+redS[r][1]+redS[r][2]+redS[r][3];
    float SS=redQ[r][0]+redQ[r][1]+redQ[r][2]+redQ[r][3];
    float m=S*(1.0f/256.0f);
    float rs=rsqrtf(SS*(1.0f/256.0f)-m*m+1e-5f);
    ysl[r*256+cl]=(snl[r*256+cl]-m)*rs*ls_g[cl]+ls_b[cl];
  }
  __syncthreads();
  {
    int col=t&255, kh=t>>8;
    const uint4* w4=(const uint4*)(M2h + (size_t)col*256 + kh*128);
    float a0=0.f,a1=0.f;
#pragma unroll 4
    for(int kk=0;kk<16;kk++){
      uint4 u=w4[kk]; float w[8]; up8(u,w);
      int kb=kh*128+kk*8;
#pragma unroll
      for(int j=0;j<8;j++){ a0+=ysl[kb+j]*w[j]; a1+=ysl[256+kb+j]*w[j]; }
    }
    pp[kh][0][col]=a0; pp[kh][1][col]=a1;
  }
  __syncthreads();
  {
    int col=t&255, r=t>>8;
    qs_out[(size_t)b*2048 + (roff+r)*256 + col] = pp[0][r][col]+pp[1][r][col];
  }
}

extern "C" void kernel_launch(void* const* d_in, const int* in_sizes, int n_in,
                              void* d_out, int out_size, void* d_ws, size_t ws_size,
                              hipStream_t stream){
  const float* inputs=(const float*)d_in[0];
  const float* sinit =(const float*)d_in[1];
  const float* Wq =(const float*)d_in[2];
  const float* Wk =(const float*)d_in[3];
  const float* Wv =(const float*)d_in[4];
  const float* Wih=(const float*)d_in[5];
  const float* Whh=(const float*)d_in[6];
  const float* bih=(const float*)d_in[7];
  const float* bhh=(const float*)d_in[8];
  const float* lin_g=(const float*)d_in[9];
  const float* lin_b=(const float*)d_in[10];
  const float* ls_g=(const float*)d_in[11];
  const float* ls_b=(const float*)d_in[12];
  const float* lm_g=(const float*)d_in[13];
  const float* lm_b=(const float*)d_in[14];
  const float* W1=(const float*)d_in[15];
  const float* b1=(const float*)d_in[16];
  const float* W2=(const float*)d_in[17];
  const float* b2=(const float*)d_in[18];

  char* w=(char*)d_ws;
  __half* x   =(__half*)w; w += (size_t)BB*NN*DD*2;         // 134.2 MB
  float* qs   =(float*)w;  w += 512*256*4;
  float* slots=(float*)w;  w += 512*256*4;
  float* pagg =(float*)w;  w += (size_t)1024*2064*4;        // 8.45 MB
  __half* M2h =(__half*)w; w += 256*256*2;
  __half* Wihh=(__half*)w; w += 768*256*2;
  __half* Whhh=(__half*)w; w += 768*256*2;
  __half* W1h =(__half*)w; w += 1024*256*2;
  __half* W2h =(__half*)w; w += 256*1024*2;
  __half* Wvh =(__half*)w; w += 256*256*2;

  hipLaunchKernelGGL(k_prep, dim3(1088), dim3(256), 0, stream,
                     Wih,Whh,W1,W2,Wv,sinit, Wihh,Whhh,W1h,W2h,Wvh,slots);
  hipLaunchKernelGGL(k_M,    dim3(256),  dim3(256), 0, stream, Wq, Wk, M2h);
  hipLaunchKernelGGL(k_ln_x, dim3(65536),dim3(256), 0, stream, inputs, lin_g, lin_b, x);
  hipLaunchKernelGGL(k_pre,  dim3(512),  dim3(256), 0, stream, slots, ls_g, ls_b, M2h, qs);
  for(int it=0; it<NITER; ++it){
    int last = (it==NITER-1);
    float* dst = last ? (float*)d_out : slots;
    hipLaunchKernelGGL(k_att,  dim3(1024), dim3(256), 0, stream, x, qs, pagg);
    hipLaunchKernelGGL(k_tail, dim3(256),  dim3(512), 0, stream,
                       pagg, Wvh, slots, Wihh, Whhh, bih, bhh,
                       lm_g, lm_b, W1h, b1, W2h, b2, ls_g, ls_b, M2h,
                       dst, qs, last);
  }
}